// Round 6
// baseline (139.408 us; speedup 1.0000x reference)
//
#include <hip/hip_runtime.h>
#include <hip/hip_fp16.h>
#include <stdint.h>

// Problem constants (fixed by the reference):
#define MQ 8192   // N*C queries
#define NK 1024   // K codewords
#define DD 1024   // H*W
#define DELTA 2.0f  // screen slack: covers ~2x worst-case approx error (~0.75)

typedef _Float16 half8_t __attribute__((ext_vector_type(8)));
typedef _Float16 half4_t __attribute__((ext_vector_type(4)));
typedef float    floatx4 __attribute__((ext_vector_type(4)));

// async global->LDS, 16B per lane; LDS dest is wave-uniform base + lane*16
#define GLOAD_LDS16(gp, lp)                                                   \
  __builtin_amdgcn_global_load_lds(                                           \
      (const __attribute__((address_space(1))) void*)(gp),                    \
      (__attribute__((address_space(3))) void*)(lp), 16, 0, 0)

// ---------- prep: f16 hi-parts only (screen needs no lo split) + csqr ----------
__global__ void k_prep(const float* __restrict__ x, const float* __restrict__ cb,
                       _Float16* __restrict__ ah, _Float16* __restrict__ bh,
                       float* __restrict__ csqr) {
  const int bid = blockIdx.x;
  const int t = threadIdx.x;
  if (bid < 8192) {
    int i = bid * 256 + t;
    float4 v = ((const float4*)x)[i];
    float vv[4] = {v.x, v.y, v.z, v.w};
    half4_t h;
#pragma unroll
    for (int j = 0; j < 4; ++j) h[j] = (_Float16)vv[j];
    ((half4_t*)ah)[i] = h;
  } else {
    int k = bid - 8192;
    float4 v = ((const float4*)(cb + (size_t)k * DD))[t];
    float vv[4] = {v.x, v.y, v.z, v.w};
    half4_t h;
    double s = 0.0;
#pragma unroll
    for (int j = 0; j < 4; ++j) {
      h[j] = (_Float16)vv[j];
      s += (double)vv[j] * (double)vv[j];
    }
    ((half4_t*)(bh + (size_t)k * DD))[t] = h;
    for (int m = 32; m >= 1; m >>= 1) s += __shfl_xor(s, m, 64);
    __shared__ double red[4];
    if ((t & 63) == 0) red[t >> 6] = s;
    __syncthreads();
    if (t == 0) csqr[k] = (float)(red[0] + red[1] + red[2] + red[3] - 1024.0);
  }
}

__device__ __forceinline__ unsigned sortable_u32(float f) {
  unsigned u = __float_as_uint(f);
  return (u & 0x80000000u) ? ~u : (u | 0x80000000u);
}

// ---------------- phase A: hi*hi screen GEMM, K-split x2, f16 partial scores ----------------
// kz=0: S0[m][n] = f16(csqr[n] - 2*dot(xh[m], ch[n])[k 0..511])
// kz=1: S1[m][n] = f16(          - 2*dot(xh[m], ch[n])[k 512..1023])
// 128x128 tile; grid (8,64,2) = 1024 blocks = 4 blocks/CU (R3/R4 lesson: keep the
// 128^2 tile's 16 MFMA/wave/barrier, raise occupancy via K-split, not tile shrink).
__global__ __launch_bounds__(256) void k_screen(
    const _Float16* __restrict__ Ah, const _Float16* __restrict__ Bh,
    const float* __restrict__ csqr, _Float16* __restrict__ S0,
    _Float16* __restrict__ S1) {
  __shared__ _Float16 sA[128 * 32];  // row-major [row][32], unpadded
  __shared__ _Float16 sB[128 * 32];  // (global_load_lds forbids padding)

  const int tid = threadIdx.x;
  const int bn = blockIdx.x;          // 0..7   (N tiles)
  const int bm = blockIdx.y;          // 0..63  (M tiles)
  const int kz = blockIdx.z;          // 0..1   (K halves)
  const int m0 = bm * 128, n0 = bn * 128;
  const int kbase = kz * 512;
  const int wave = tid >> 6, lane = tid & 63;
  const int wm = wave & 1, wn = wave >> 1;
  const int quad = lane >> 4, l15 = lane & 15;

  floatx4 acc[4][4];
#pragma unroll
  for (int i = 0; i < 4; ++i)
#pragma unroll
    for (int j = 0; j < 4; ++j) acc[i][j] = (floatx4){0.f, 0.f, 0.f, 0.f};

  const int r0 = tid >> 2;
  const int c0 = (tid & 3) * 8;
  _Float16* sAw = sA + wave * 512;
  _Float16* sAw2 = sA + 2048 + wave * 512;
  _Float16* sBw = sB + wave * 512;
  _Float16* sBw2 = sB + 2048 + wave * 512;

  for (int kb = 0; kb < 16; ++kb) {  // K=512 per z-half
    const int kk = kbase + kb * 32;
    __syncthreads();
    GLOAD_LDS16(Ah + (size_t)(m0 + r0) * DD + kk + c0, sAw);
    GLOAD_LDS16(Ah + (size_t)(m0 + 64 + r0) * DD + kk + c0, sAw2);
    GLOAD_LDS16(Bh + (size_t)(n0 + r0) * DD + kk + c0, sBw);
    GLOAD_LDS16(Bh + (size_t)(n0 + 64 + r0) * DD + kk + c0, sBw2);
    __syncthreads();

    half8_t af[4], bf[4];
#pragma unroll
    for (int i = 0; i < 4; ++i)
      af[i] = *(const half8_t*)(sA + (wm * 64 + i * 16 + l15) * 32 + quad * 8);
#pragma unroll
    for (int j = 0; j < 4; ++j)
      bf[j] = *(const half8_t*)(sB + (wn * 64 + j * 16 + l15) * 32 + quad * 8);
#pragma unroll
    for (int i = 0; i < 4; ++i)
#pragma unroll
      for (int j = 0; j < 4; ++j)
        acc[i][j] = __builtin_amdgcn_mfma_f32_16x16x32_f16(af[i], bf[j], acc[i][j], 0, 0, 0);
  }

  // epilogue: write f16 partial scores (csqr folded into the kz=0 half only)
  _Float16* __restrict__ Sk = kz ? S1 : S0;
  float csv[4];
#pragma unroll
  for (int j = 0; j < 4; ++j) csv[j] = kz ? 0.f : csqr[n0 + wn * 64 + j * 16 + l15];
#pragma unroll
  for (int i = 0; i < 4; ++i)
#pragma unroll
    for (int r = 0; r < 4; ++r) {
      const int row = m0 + wm * 64 + i * 16 + quad * 4 + r;  // C/D: col=lane&15, row=quad*4+reg
#pragma unroll
      for (int j = 0; j < 4; ++j) {
        const int col = n0 + wn * 64 + j * 16 + l15;
        Sk[(size_t)row * NK + col] = (_Float16)(csv[j] - 2.0f * acc[i][j][r]);
      }
    }
}

// -------- phase B: wave-per-row scan + exact fp32 refine + gather/write --------
__global__ __launch_bounds__(256) void k_refine(
    const _Float16* __restrict__ S0, const _Float16* __restrict__ S1,
    const float* __restrict__ x, const float* __restrict__ cb,
    float* __restrict__ out, int both) {
  const int wave = threadIdx.x >> 6, lane = threadIdx.x & 63;
  const int m = blockIdx.x * 4 + wave;

  // scan summed score row: 16 f16 per lane from each half
  const half8_t* R0 = (const half8_t*)(S0 + (size_t)m * NK);
  const half8_t* R1 = (const half8_t*)(S1 + (size_t)m * NK);
  half8_t a0 = R0[lane * 2], a1 = R0[lane * 2 + 1];
  half8_t b0 = R1[lane * 2], b1 = R1[lane * 2 + 1];
  float sc[16];
#pragma unroll
  for (int k = 0; k < 8; ++k) {
    sc[k] = (float)a0[k] + (float)b0[k];
    sc[8 + k] = (float)a1[k] + (float)b1[k];
  }
  float mn = sc[0];
#pragma unroll
  for (int k = 1; k < 16; ++k) mn = fminf(mn, sc[k]);
  for (int o = 1; o <= 32; o <<= 1) mn = fminf(mn, __shfl_xor(mn, o, 64));
  const float thr = mn + DELTA;

  // collect candidate indices (wave-uniform list in registers)
  int cand[12];
  int nc = 0;
#pragma unroll
  for (int s = 0; s < 16; ++s) {
    unsigned long long msk = __ballot(sc[s] <= thr);
    while (msk && nc < 12) {
      int l = __builtin_ctzll(msk);
      msk &= msk - 1;
      cand[nc++] = l * 16 + s;  // lane l holds cols l*16 + s
    }
  }

  int widx;
  if (nc == 1) {
    widx = cand[0];  // ~93% of rows: single candidate, skip exact pass entirely
  } else {
    // x row in registers: lane covers floats [q*256 + lane*4, +4)
    const float4* xr4 = (const float4*)(x + (size_t)m * DD);
    float4 xr[4];
#pragma unroll
    for (int q = 0; q < 4; ++q) xr[q] = xr4[q * 64 + lane];

    unsigned long long best = ~0ULL;
    for (int c = 0; c < nc; ++c) {
      const float4* c4 = (const float4*)(cb + (size_t)cand[c] * DD);
      float d = 0.f;
#pragma unroll
      for (int q = 0; q < 4; ++q) {
        float4 v = c4[q * 64 + lane];
        float dx = xr[q].x - v.x, dy = xr[q].y - v.y;
        float dz = xr[q].z - v.z, dw = xr[q].w - v.w;
        d += dx * dx + dy * dy + dz * dz + dw * dw;
      }
      for (int o = 1; o <= 32; o <<= 1) d += __shfl_xor(d, o, 64);
      unsigned long long key =
          ((unsigned long long)sortable_u32(d) << 32) | (unsigned)cand[c];
      best = key < best ? key : best;  // ties -> lowest index (np argmin)
    }
    widx = (int)(best & 0xFFFFFFFFULL);
  }

  // gather winner, write output(s)
  const float4* w4 = (const float4*)(cb + (size_t)widx * DD);
  float4* o0 = (float4*)(out + (size_t)m * DD);
  float4* o1 = (float4*)(out + (size_t)(m + MQ) * DD);
#pragma unroll
  for (int q = 0; q < 4; ++q) {
    float4 v = w4[q * 64 + lane];
    o0[q * 64 + lane] = v;
    if (both) o1[q * 64 + lane] = v;
  }
}

// d2d copy lower output copy -> upper (only when S had to live in d_out's top)
__global__ void k_copy(const float4* __restrict__ src, float4* __restrict__ dst) {
  int i = blockIdx.x * 256 + threadIdx.x;
  dst[i] = src[i];
}

extern "C" void kernel_launch(void* const* d_in, const int* in_sizes, int n_in,
                              void* d_out, int out_size, void* d_ws, size_t ws_size,
                              hipStream_t stream) {
  const float* x = (const float*)d_in[0];
  const float* cb = (const float*)d_in[1];
  float* out = (float*)d_out;
  char* ob = (char*)d_out;

  const size_t MB = 1024 * 1024;
  // Ah/Bh scratch lives in d_out (dead before any output write).
  _Float16* Ah = (_Float16*)(ob);              // [0,16MB)
  _Float16* Bh = (_Float16*)(ob + 16 * MB);    // [16,18MB)

  // S0/S1 (16MB each) + csqr: prefer d_ws, guarded by ws_size (R1 lesson: an
  // unguarded d_ws overflow corrupted the harness's pristine inputs). Measured
  // ws_size is 256 MiB, but keep the d_out fallback: S0/S1 in [32,64MB), refine
  // writes only the lower output copy, k_copy fills the upper afterwards.
  const bool ws_ok = ws_size >= 32 * MB + 4096;
  _Float16 *S0, *S1;
  float* csqr;
  if (ws_ok) {
    S0 = (_Float16*)d_ws;
    S1 = (_Float16*)((char*)d_ws + 16 * MB);
    csqr = (float*)((char*)d_ws + 32 * MB);
  } else {
    S0 = (_Float16*)(ob + 32 * MB);
    S1 = (_Float16*)(ob + 48 * MB);
    csqr = (float*)(ob + 18 * MB);
  }

  k_prep<<<8192 + 1024, 256, 0, stream>>>(x, cb, Ah, Bh, csqr);
  k_screen<<<dim3(8, 64, 2), 256, 0, stream>>>(Ah, Bh, csqr, S0, S1);
  k_refine<<<2048, 256, 0, stream>>>(S0, S1, x, cb, out, ws_ok ? 1 : 0);
  if (!ws_ok) k_copy<<<8192, 256, 0, stream>>>((const float4*)out, (float4*)(ob + 32 * MB));
}